// Round 2
// baseline (94.617 us; speedup 1.0000x reference)
//
#include <hip/hip_runtime.h>
#include <math.h>

// out[n,o] = exp(A)*cos(B)
//   A = sum_i ln(R)*Wr - K*Wi ;  B = sum_i ln(R)*Wi + K*Wr
//   R = 1 + g*(|x|-1),  K = pi*(x<0)*g,  g = clip(G,0,1)
// n=8192, i=o=128.
//
// R13 = R12 with the row-plane loads FORCED onto the scalar pipe.
// R12 post-mortem: readfirstlane-uniform address did NOT scalarize (xt is
// kernel-written -> no no-clobber proof -> stayed VMEM). Uniform-address
// global_load_dwordx4 writes back 1KB/instr (64 lanes x 16B) -> worse than
// the LDS broadcast it replaced (main ~43us, total 91).
// Fix: inline-asm s_load_dwordx16 -> one 64B SMEM load per wave-iter
// delivering am1[0..7]|ps[0..7] into a 512-bit SGPR tuple (s_waitcnt
// lgkmcnt(0) fused inside the asm, so no reordering hazard). v_pk_fma_f32
// consumes the aligned SGPR pairs directly (1 scalar operand is legal).
// Main-loop floor: 8 v_log (TRANS 64cy) + 20 pk_fma (40cy issue) + 1 VMEM
// (wq 16B/lane, L2-hit) per wave-iter; 1024 wave-iters/CU -> ~7us TRANS,
// ~7us VMEM-return, overlapped -> main ~12-15us.
// Geometry: RPB=8, NT=512 (o:128 x q:4 i-quarters), 1024 blocks x 8 waves,
// launch_bounds(512,8), 16KB LDS epilogue overlay only.

#define NROWS 8192
#define DIM   128
#define RPB   8
#define NT    512
#define IQ    32
#define PI_F  3.14159265358979323846f
#define LN2_F 0.69314718055994530942f

typedef float v2f    __attribute__((ext_vector_type(2)));
typedef float f32x16 __attribute__((ext_vector_type(16)));

static __device__ __forceinline__ v2f vfma2(v2f a, v2f b, v2f c) {
    return __builtin_elementwise_fma(a, b, c);
}

// Combined prep, grid = 64 + 1024 blocks x 256:
//   blocks [0,64):    wq[i*DIM+o] = (ln2*wr, ln2*wi, g, g/ln2)
//   blocks [64,1088): xt[db][i][0..7] = |x|-1 rows 0..7,
//                     xt[db][i][8..15] = pi*(x<0) rows 0..7   (64B/record)
__global__ __launch_bounds__(256) void prep(
    const float* __restrict__ x,
    const float* __restrict__ Wr, const float* __restrict__ Wi,
    const float* __restrict__ G,
    float4* __restrict__ wq, float* __restrict__ xt)
{
    const int b = blockIdx.x;
    if (b < 64) {
        int t = b * 256 + threadIdx.x;
        float g  = fminf(fmaxf(G[t], 0.0f), 1.0f);
        wq[t] = make_float4(LN2_F * Wr[t], LN2_F * Wi[t], g, g * (1.0f / LN2_F));
    } else {
        const int db = b - 64;                       // data block 0..1023
        const float4* xb = (const float4*)(x + (size_t)db * RPB * DIM);
        float4 v = xb[threadIdx.x];                  // coalesced 4KB tile read
        int e = threadIdx.x * 4;
        int i = e & (DIM - 1), r = e >> 7;           // float4 stays in one row
        float* op = xt + (size_t)db * (DIM * 16);
        float vv[4] = {v.x, v.y, v.z, v.w};
#pragma unroll
        for (int k = 0; k < 4; ++k) {
            op[(i + k) * 16 + r]     = fabsf(vv[k]) - 1.0f;
            op[(i + k) * 16 + 8 + r] = (vv[k] < 0.0f) ? PI_F : 0.0f;
        }
    }
}

template <bool PACKED>
__global__ __launch_bounds__(NT, 8) void main_kernel(
    const float* __restrict__ x, const float4* __restrict__ wq,
    const float* __restrict__ xt,
    const float* __restrict__ Wr, const float* __restrict__ Wi,
    const float* __restrict__ G, float* __restrict__ out)
{
    // 16 KB. PACKED path uses sbuf only in the epilogue overlay
    // [4][RPB][DIM] (A partials then B partials). Fallback also uses the
    // first 8KB as am1/ps planes during the main loop.
    __shared__ float sbuf[4 * RPB * DIM];

    const int tid   = threadIdx.x;
    const int o     = tid & (DIM - 1);
    const int q     = tid >> 7;            // i-quarter 0..3 (wave-uniform)
    const int nbase = blockIdx.x * RPB;

    v2f accA[4], accB[4];
#pragma unroll
    for (int p = 0; p < 4; ++p) { accA[p] = (v2f){0.f, 0.f}; accB[p] = (v2f){0.f, 0.f}; }

    const int ibase = q * IQ;

    if constexpr (PACKED) {
        const float4* wqp = wq + ibase * DIM + o;
        // Wave-uniform base for the row planes (forced uniform for the "s"
        // asm constraint; value is uniform by construction).
        const int qu = __builtin_amdgcn_readfirstlane(q);
        const float* xrow = xt + (size_t)blockIdx.x * (DIM * 16)
                               + (size_t)qu * (IQ * 16);

        float4 wcur = wqp[0];   // wq software pipeline (VMEM)

#pragma unroll 2
        for (int ii = 0; ii < IQ; ++ii) {
            // 64B scalar load: am1[0..7] | ps[0..7] for i = ibase+ii.
            // Wait fused inside the asm -> the tuple is complete before any
            // use; no compiler-reordering hazard. SMEM pipe, 64B writeback
            // (vs 1KB/instr for the old broadcast ds_read/global_load).
            f32x16 rp;
            const float* p = xrow + ii * 16;
            asm volatile("s_load_dwordx16 %0, %1, 0x0\n\t"
                         "s_waitcnt lgkmcnt(0)"
                         : "=&s"(rp) : "s"(p));

            float4 wnxt = wqp[((ii + 1) & (IQ - 1)) * DIM];  // prefetch, wraps

            const float wrl = wcur.x, wil = wcur.y, g = wcur.z, gq = wcur.w;
            const float ngwi = -gq * wil;     // == -g*wi
            const float gwr  =  gq * wrl;     // ==  g*wr
            const v2f gg2   = {g, g};
            const v2f wrl2  = {wrl, wrl};
            const v2f wil2  = {wil, wil};
            const v2f ngwi2 = {ngwi, ngwi};
            const v2f gwr2  = {gwr, gwr};
            const v2f one2  = {1.0f, 1.0f};

            // ax/ay (and sx/sy) are adjacent even-aligned SGPRs from the
            // s_load tuple -> legal single-scalar operand of v_pk_fma_f32.
#define ROWPAIR(ax, ay, sx, sy, idx)                                        \
            do {                                                            \
                v2f t2 = vfma2((v2f){ax, ay}, gg2, one2);                   \
                v2f l2 = { __log2f(t2.x), __log2f(t2.y) };                  \
                v2f s2 = {sx, sy};                                          \
                accA[idx] = vfma2(l2, wrl2, vfma2(s2, ngwi2, accA[idx]));   \
                accB[idx] = vfma2(l2, wil2, vfma2(s2, gwr2,  accB[idx]));   \
            } while (0)

            ROWPAIR(rp[0], rp[1], rp[8],  rp[9],  0);
            ROWPAIR(rp[2], rp[3], rp[10], rp[11], 1);
            ROWPAIR(rp[4], rp[5], rp[12], rp[13], 2);
            ROWPAIR(rp[6], rp[7], rp[14], rp[15], 3);
#undef ROWPAIR

            wcur = wnxt;
        }
    } else {
        // Fallback (no workspace): original LDS-plane path.
        float* am1p = sbuf;               // [DIM][RPB]
        float* psp  = sbuf + DIM * RPB;   // [DIM][RPB]
        {
            const float* xb = x + (size_t)nbase * DIM;
            float2 v = ((const float2*)xb)[tid];
            int e = tid * 2;
            int i = e & (DIM - 1), r = e >> 7;
            am1p[i * RPB + r]       = fabsf(v.x) - 1.0f;
            am1p[(i + 1) * RPB + r] = fabsf(v.y) - 1.0f;
            psp[i * RPB + r]        = (v.x < 0.0f) ? PI_F : 0.0f;
            psp[(i + 1) * RPB + r]  = (v.y < 0.0f) ? PI_F : 0.0f;
        }
        __syncthreads();

#pragma unroll 2
        for (int ii = 0; ii < IQ; ++ii) {
            const int i = ibase + ii;
            float g   = fminf(fmaxf(G[i * DIM + o], 0.0f), 1.0f);
            float wrl = LN2_F * Wr[i * DIM + o];
            float wil = LN2_F * Wi[i * DIM + o];
            float gq  = g * (1.0f / LN2_F);
            const float ngwi = -gq * wil;
            const float gwr  =  gq * wrl;
            const v2f gg2   = {g, g};
            const v2f wrl2  = {wrl, wrl};
            const v2f wil2  = {wil, wil};
            const v2f ngwi2 = {ngwi, ngwi};
            const v2f gwr2  = {gwr, gwr};
            const v2f one2  = {1.0f, 1.0f};

            const float4* a4 = (const float4*)(am1p + i * RPB);
            const float4* p4 = (const float4*)(psp  + i * RPB);
            float4 a03 = a4[0], a47 = a4[1];
            float4 s03 = p4[0], s47 = p4[1];

#define ROWPAIR(mx, my, sx, sy, idx)                                        \
            do {                                                            \
                v2f t2 = vfma2((v2f){mx, my}, gg2, one2);                   \
                v2f l2 = { __log2f(t2.x), __log2f(t2.y) };                  \
                v2f s2 = {sx, sy};                                          \
                accA[idx] = vfma2(l2, wrl2, vfma2(s2, ngwi2, accA[idx]));   \
                accB[idx] = vfma2(l2, wil2, vfma2(s2, gwr2,  accB[idx]));   \
            } while (0)

            ROWPAIR(a03.x, a03.y, s03.x, s03.y, 0);
            ROWPAIR(a03.z, a03.w, s03.z, s03.w, 1);
            ROWPAIR(a47.x, a47.y, s47.x, s47.y, 2);
            ROWPAIR(a47.z, a47.w, s47.z, s47.w, 3);
#undef ROWPAIR
        }
    }

    // Epilogue: q-reduce via one 16 KB buffer, A then B.
    float* pP = sbuf;                        // [4][RPB][DIM]
    const int c = tid * 2;
    const int r = c >> 7, oo = c & (DIM - 1);

    if constexpr (!PACKED) __syncthreads();  // waves done reading planes
#pragma unroll
    for (int p = 0; p < 4; ++p) {
        pP[q * (RPB * DIM) + (2 * p) * DIM + o]     = accA[p].x;
        pP[q * (RPB * DIM) + (2 * p + 1) * DIM + o] = accA[p].y;
    }
    __syncthreads();
    v2f A = {0.f, 0.f};
#pragma unroll
    for (int qq = 0; qq < 4; ++qq)
        A += *(const v2f*)&pP[qq * (RPB * DIM) + r * DIM + oo];
    __syncthreads();   // before overwriting with B partials
#pragma unroll
    for (int p = 0; p < 4; ++p) {
        pP[q * (RPB * DIM) + (2 * p) * DIM + o]     = accB[p].x;
        pP[q * (RPB * DIM) + (2 * p + 1) * DIM + o] = accB[p].y;
    }
    __syncthreads();
    v2f B = {0.f, 0.f};
#pragma unroll
    for (int qq = 0; qq < 4; ++qq)
        B += *(const v2f*)&pP[qq * (RPB * DIM) + r * DIM + oo];

    float2 res;
    res.x = __expf(A.x) * __cosf(B.x);
    res.y = __expf(A.y) * __cosf(B.y);
    *(float2*)&out[(size_t)(nbase + r) * DIM + oo] = res;
}

extern "C" void kernel_launch(void* const* d_in, const int* in_sizes, int n_in,
                              void* d_out, int out_size, void* d_ws, size_t ws_size,
                              hipStream_t stream) {
    const float* x  = (const float*)d_in[0];
    const float* Wr = (const float*)d_in[1];
    const float* Wi = (const float*)d_in[2];
    const float* G  = (const float*)d_in[3];
    float* out = (float*)d_out;

    const size_t wq_bytes = (size_t)DIM * DIM * sizeof(float4);               // 256 KB
    const size_t xt_bytes = (size_t)(NROWS / RPB) * DIM * 16 * sizeof(float); // 8 MB
    if (ws_size >= wq_bytes + xt_bytes) {
        float4* wq = (float4*)d_ws;
        float*  xt = (float*)((char*)d_ws + wq_bytes);
        prep<<<64 + NROWS / RPB, 256, 0, stream>>>(x, Wr, Wi, G, wq, xt);
        main_kernel<true><<<NROWS / RPB, NT, 0, stream>>>(x, wq, xt,
                                                          nullptr, nullptr, nullptr, out);
    } else {
        main_kernel<false><<<NROWS / RPB, NT, 0, stream>>>(x, nullptr, nullptr,
                                                           Wr, Wi, G, out);
    }
}

// Round 3
// 88.546 us; speedup vs baseline: 1.0686x; 1.0686x over previous
//
#include <hip/hip_runtime.h>
#include <math.h>

// out[n,o] = exp(A)*cos(B)
//   A = sum_i ln(R)*Wr - K*Wi ;  B = sum_i ln(R)*Wi + K*Wr
//   R = 1 + g*(|x|-1),  K = pi*(x<0)*g,  g = clip(G,0,1)
// n=8192, i=o=128.
//
// R14: workspace-free probe + register-pressure fix.
// R12/R13 post-mortem: both broadcast-load reroutes (uniform global, forced
// s_load) regressed -> that theory is dead. Fresh budget readout: every
// round's top-5 is the 256MiB ws-poison fill at ~41us INSIDE the timed
// stream (48% of total), and it exists only because we request ws. This
// round: (a) drop ws entirely (fallback math path, verified numerics, no
// prep kernel) to probe whether the poison is conditional on ws use;
// (b) launch_bounds 8->4 waves/EU: the old (512,8) caps VGPR at 64, right
// at the loop's live set -> scheduler can't hoist loads -> per-iter memory
// latency serializes (main ~42us vs ~9us issue floor). (512,4) gives 128
// VGPRs; unroll 4 lets all 12 operand loads batch at the top of the body.
// Readout: ~45-55 fill-gone / ~65-75 LB-fix only / ~85-90 both null / >92
// LB hurt.
// Geometry: RPB=8, NT=512 (o:128 x q:4 i-quarters), 1024 blocks,
// 16KB LDS (planes -> epilogue overlay).

#define NROWS 8192
#define DIM   128
#define RPB   8
#define NT    512
#define IQ    32
#define PI_F  3.14159265358979323846f
#define LN2_F 0.69314718055994530942f

typedef float v2f __attribute__((ext_vector_type(2)));

static __device__ __forceinline__ v2f vfma2(v2f a, v2f b, v2f c) {
    return __builtin_elementwise_fma(a, b, c);
}

__global__ __launch_bounds__(NT, 4) void main_kernel(
    const float* __restrict__ x,
    const float* __restrict__ Wr, const float* __restrict__ Wi,
    const float* __restrict__ G, float* __restrict__ out)
{
    // 16 KB. Main loop: am1 plane + ps plane [DIM][RPB] each (8 KB).
    // Epilogue overlay: one partial buffer [4][RPB][DIM] (16 KB), A then B.
    __shared__ float sbuf[4 * RPB * DIM];
    float* am1p = sbuf;               // [DIM][RPB]
    float* psp  = sbuf + DIM * RPB;   // [DIM][RPB]

    const int tid   = threadIdx.x;
    const int o     = tid & (DIM - 1);
    const int q     = tid >> 7;            // i-quarter 0..3
    const int nbase = blockIdx.x * RPB;

    // Stage x tile (1024 floats): float2 coalesced read, SoA scatter.
    {
        const float* xb = x + (size_t)nbase * DIM;
        float2 v = ((const float2*)xb)[tid];
        int e = tid * 2;
        int i = e & (DIM - 1), r = e >> 7;
        am1p[i * RPB + r]       = fabsf(v.x) - 1.0f;
        am1p[(i + 1) * RPB + r] = fabsf(v.y) - 1.0f;
        psp[i * RPB + r]        = (v.x < 0.0f) ? PI_F : 0.0f;
        psp[(i + 1) * RPB + r]  = (v.y < 0.0f) ? PI_F : 0.0f;
    }
    __syncthreads();

    v2f accA[4], accB[4];
#pragma unroll
    for (int p = 0; p < 4; ++p) { accA[p] = (v2f){0.f, 0.f}; accB[p] = (v2f){0.f, 0.f}; }

    const int ibase = q * IQ;
    const int wo    = ibase * DIM + o;      // base weight index for this thread

#pragma unroll 4
    for (int ii = 0; ii < IQ; ++ii) {
        const int i  = ibase + ii;
        const int wi_idx = wo + ii * DIM;

        // Direct weight reads (L2/L3-resident: 192 KB total, shared by all
        // blocks). 12 B/lane/iter, fully coalesced. With 128-VGPR budget and
        // unroll 4 the compiler batches these 12 loads ahead of the math.
        float g   = fminf(fmaxf(G[wi_idx], 0.0f), 1.0f);   // v_med3
        float wrl = LN2_F * Wr[wi_idx];
        float wil = LN2_F * Wi[wi_idx];

        const float ngwi = -g * (wil * (1.0f / LN2_F));    // == -g*wi
        const float gwr  =  g * (wrl * (1.0f / LN2_F));    // ==  g*wr
        const v2f gg2   = {g, g};
        const v2f wrl2  = {wrl, wrl};
        const v2f wil2  = {wil, wil};
        const v2f ngwi2 = {ngwi, ngwi};
        const v2f gwr2  = {gwr, gwr};
        const v2f one2  = {1.0f, 1.0f};

        // 8 rows via 2+2 broadcast ds_read_b128 (all lanes same address).
        const float4* a4 = (const float4*)(am1p + i * RPB);
        const float4* p4 = (const float4*)(psp  + i * RPB);
        float4 a03 = a4[0], a47 = a4[1];
        float4 s03 = p4[0], s47 = p4[1];

#define ROWPAIR(mx, my, sx, sy, idx)                                        \
        do {                                                                \
            v2f t2 = vfma2((v2f){mx, my}, gg2, one2);                       \
            v2f l2 = { __log2f(t2.x), __log2f(t2.y) };                      \
            v2f s2 = {sx, sy};                                              \
            accA[idx] = vfma2(l2, wrl2, vfma2(s2, ngwi2, accA[idx]));       \
            accB[idx] = vfma2(l2, wil2, vfma2(s2, gwr2,  accB[idx]));       \
        } while (0)

        ROWPAIR(a03.x, a03.y, s03.x, s03.y, 0);
        ROWPAIR(a03.z, a03.w, s03.z, s03.w, 1);
        ROWPAIR(a47.x, a47.y, s47.x, s47.y, 2);
        ROWPAIR(a47.z, a47.w, s47.z, s47.w, 3);
#undef ROWPAIR
    }

    // Epilogue: q-reduce via one 16 KB buffer, A then B (planes dead now).
    float* pP = sbuf;                        // [4][RPB][DIM]
    const int c = tid * 2;
    const int r = c >> 7, oo = c & (DIM - 1);

    __syncthreads();   // all waves done reading planes
#pragma unroll
    for (int p = 0; p < 4; ++p) {
        pP[q * (RPB * DIM) + (2 * p) * DIM + o]     = accA[p].x;
        pP[q * (RPB * DIM) + (2 * p + 1) * DIM + o] = accA[p].y;
    }
    __syncthreads();
    v2f A = {0.f, 0.f};
#pragma unroll
    for (int qq = 0; qq < 4; ++qq)
        A += *(const v2f*)&pP[qq * (RPB * DIM) + r * DIM + oo];
    __syncthreads();   // before overwriting with B partials
#pragma unroll
    for (int p = 0; p < 4; ++p) {
        pP[q * (RPB * DIM) + (2 * p) * DIM + o]     = accB[p].x;
        pP[q * (RPB * DIM) + (2 * p + 1) * DIM + o] = accB[p].y;
    }
    __syncthreads();
    v2f B = {0.f, 0.f};
#pragma unroll
    for (int qq = 0; qq < 4; ++qq)
        B += *(const v2f*)&pP[qq * (RPB * DIM) + r * DIM + oo];

    float2 res;
    res.x = __expf(A.x) * __cosf(B.x);
    res.y = __expf(A.y) * __cosf(B.y);
    *(float2*)&out[(size_t)(nbase + r) * DIM + oo] = res;
}

extern "C" void kernel_launch(void* const* d_in, const int* in_sizes, int n_in,
                              void* d_out, int out_size, void* d_ws, size_t ws_size,
                              hipStream_t stream) {
    const float* x  = (const float*)d_in[0];
    const float* Wr = (const float*)d_in[1];
    const float* Wi = (const float*)d_in[2];
    const float* G  = (const float*)d_in[3];
    float* out = (float*)d_out;

    // Workspace intentionally UNUSED this round: probing whether the 256MiB
    // ws-poison fill (~41us/iter, 48% of total) is conditional on ws use.
    (void)d_ws; (void)ws_size;

    main_kernel<<<NROWS / RPB, NT, 0, stream>>>(x, Wr, Wi, G, out);
}